// Round 9
// baseline (3579.406 us; speedup 1.0000x reference)
//
#include <hip/hip_runtime.h>

#define NB    16      // batches
#define NPTS  100000  // points per batch
#define NCH   16      // channels
#define KSEL  1024    // samples
#define SLOTS 8       // blocks per batch
#define TPB   512     // threads per fps block
#define CHUNK 12500   // NPTS / SLOTS
#define PPT   25      // ceil(CHUNK / TPB)
#define MAGA  0x19u   // 5-bit magic, key words    (never 0, never 0xAA-pattern)
#define MAGB  0x13u   // 5-bit magic, payload words

typedef unsigned long long u64;
typedef unsigned int u32;

// d_ws layout (bytes):
//   [4096, 69632)   : mailboxes u64[par=2][NB][reader=8][writer=8][word=4]
//                     (private row per reader: 8 writers x 32B = 256B = 2 lines,
//                      polled by exactly ONE wave -> no same-line poll contention)
//   [131072, 196608): idx list int[NB][KSEL]
//
// Record words (tag+magic in EVERY u64 -> stale/torn/poison self-rejecting):
//   word0 key = val_bits(32) | invidx(17) | tag(10) | MAGA(5)  (u64 max == winner)
//   word1..3  = coord_bits(32) | invidx(17) | tag(10) | MAGB(5)  (x,y,z)
// invidx = 131071 - idx  (max invidx == min idx -> first-index tie-break).
// tag = i+1 (1..1023, never 0 -> memset-0 / 0xAA never match). All ops relaxed
// agent-scope atomics (device-coherent point = memory-side L3). Parity
// double-buffer prevents overwrite-before-read: a writer reaches tag i+3 only
// after ALL readers consumed i+1 (its i+2 poll requires everyone's i+2 publish,
// which requires their i+1 consumption) -> 2 buffers suffice.

__device__ __forceinline__ void combine(float ov, int oi, float& v, int& i) {
  if (ov > v || (ov == v && oi < i)) { v = ov; i = oi; }
}

__global__ __launch_bounds__(TPB, 1)
void fps_kernel(const float* __restrict__ points, const int* __restrict__ start_idx,
                u64* __restrict__ ws_cand, int* __restrict__ ws_idx) {
  const int raw  = blockIdx.x;
  const int b    = raw >> 3;           // batch
  const int slot = raw & 7;            // this block's writer/reader id

  const int tid  = threadIdx.x;
  const int lane = tid & 63;
  const int wid  = tid >> 6;           // 8 waves

  const int base = slot * CHUNK;
  const float* __restrict__ pb = points + (size_t)b * NPTS * NCH;

  // ---- load xyz into registers, init min_d ----
  float px[PPT], py[PPT], pz[PPT], md[PPT];
  #pragma unroll
  for (int k = 0; k < PPT; ++k) {
    const int li = tid + (k << 9);
    const bool valid = li < CHUNK;
    float4 p = make_float4(0.f, 0.f, 0.f, 0.f);
    if (valid) p = *reinterpret_cast<const float4*>(pb + (size_t)(base + li) * NCH);
    px[k] = p.x; py[k] = p.y; pz[k] = p.z;
    md[k] = valid ? __builtin_inff() : -__builtin_inff();
  }
  #pragma unroll
  for (int k = 0; k < PPT; ++k)   // keep-live guard
    asm volatile("" : "+v"(px[k]), "+v"(py[k]), "+v"(pz[k]), "+v"(md[k]));

  __shared__ float s_rv[8];            // per-wave candidates (b1-protected)
  __shared__ int   s_ri[8];
  __shared__ float s_wx, s_wy, s_wz;   // winner broadcast (b2-protected)

  // ---- initial selected point ----
  const int sidx = start_idx[b];
  float sx, sy, sz;
  {
    const float4 p = *reinterpret_cast<const float4*>(pb + (size_t)sidx * NCH);
    sx = p.x; sy = p.y; sz = p.z;
  }
  if (slot == 0 && tid == 0) ws_idx[b * KSEL] = sidx;

  for (int i = 0; i < KSEL - 1; ++i) {
    const int par = i & 1;
    // 256 u64 per (par,b): 8 reader rows x 32 u64
    u64* const bblk = ws_cand + (((size_t)par * NB + b) << 8);

    // ---- distance update + thread-local argmax (bit-exact vs numpy f32:
    //      IEEE intrinsics, left-to-right sum, no FMA contraction) ----
    float bv = -__builtin_inff();
    int   bi = 0x7fffffff;
    #pragma unroll
    for (int k = 0; k < PPT; ++k) {
      const float dx = __fsub_rn(px[k], sx);
      const float dy = __fsub_rn(py[k], sy);
      const float dz = __fsub_rn(pz[k], sz);
      const float d  = __fadd_rn(__fadd_rn(__fmul_rn(dx, dx), __fmul_rn(dy, dy)),
                                 __fmul_rn(dz, dz));
      const float m  = fminf(md[k], d);
      md[k] = m;
      if (m > bv) { bv = m; bi = base + tid + (k << 9); }  // k asc -> first-max kept
    }

    // ---- wave reduce (val, idx), first-index tie-break ----
    #pragma unroll
    for (int m = 32; m >= 1; m >>= 1) {
      const float ov = __shfl_xor(bv, m, 64);
      const int   oi = __shfl_xor(bi, m, 64);
      combine(ov, oi, bv, bi);
    }
    if (lane == 0) { s_rv[wid] = bv; s_ri[wid] = bi; }
    __syncthreads();                                   // b1: candidates ready

    // ---- block combine (every thread) ----
    bv = s_rv[0]; bi = s_ri[0];
    #pragma unroll
    for (int w = 1; w < 8; ++w) combine(s_rv[w], s_ri[w], bv, bi);

    const u32 tm = (u32)(i + 1) << 5;

    // ---- owner thread replicates {key,x,y,z} into all 8 reader rows ----
    const int local = bi - base;
    if (tid == (local & 511)) {
      const int kk = local >> 9;
      float ox = 0.f, oy = 0.f, oz = 0.f;
      #pragma unroll
      for (int k = 0; k < PPT; ++k)   // static-index select (arrays stay in VGPRs)
        if (k == kk) { ox = px[k]; oy = py[k]; oz = pz[k]; }
      const u32 inv = 131071u - (u32)bi;
      const u64 w0 = ((u64)__float_as_uint(bv) << 32) | (inv << 15) | tm | MAGA;
      const u64 meta = (u64)((inv << 15) | tm | MAGB);
      const u64 w1 = ((u64)__float_as_uint(ox) << 32) | meta;
      const u64 w2 = ((u64)__float_as_uint(oy) << 32) | meta;
      const u64 w3 = ((u64)__float_as_uint(oz) << 32) | meta;
      #pragma unroll
      for (int r = 0; r < SLOTS; ++r) {
        u64* const rec = bblk + (((size_t)r << 5) + ((size_t)slot << 2));
        __hip_atomic_store(rec + 0, w0, __ATOMIC_RELAXED, __HIP_MEMORY_SCOPE_AGENT);
        __hip_atomic_store(rec + 1, w1, __ATOMIC_RELAXED, __HIP_MEMORY_SCOPE_AGENT);
        __hip_atomic_store(rec + 2, w2, __ATOMIC_RELAXED, __HIP_MEMORY_SCOPE_AGENT);
        __hip_atomic_store(rec + 3, w3, __ATOMIC_RELAXED, __HIP_MEMORY_SCOPE_AGENT);
      }
    }

    // ---- wave 0 polls THIS block's private row (1 poller per line) ----
    if (wid == 0) {
      const u64* const row = bblk + ((size_t)slot << 5);   // 32 u64 = 2 lines
      const bool active = lane < 32;
      const int  word   = lane & 3;                        // 0=key,1=x,2=y,3=z
      const u32  want   = tm | (word == 0 ? MAGA : MAGB);
      u64 q = 0;
      for (;;) {
        if (active) q = __hip_atomic_load(row + lane, __ATOMIC_RELAXED, __HIP_MEMORY_SCOPE_AGENT);
        const bool ok = !active || (((u32)q & 0x7FFFu) == want);
        if (__all(ok)) break;
      }
      // max over the 8 key lanes (0,4,...,28): xor-net {4,8,16} closed on them
      u64 key = (active && word == 0) ? q : 0;
      #pragma unroll
      for (int m = 4; m <= 16; m <<= 1) {
        const u64 o = __shfl_xor(key, m, 64);
        if (o > key) key = o;
      }
      const u64 kmax = __shfl(key, 0, 64);                 // broadcast winner key
      const unsigned long long ball = __ballot(active && word == 0 && q == kmax);
      const int wl = __ffsll(ball) - 1;                    // winner key lane (=4*slot)
      const u32 hi = (u32)(q >> 32);
      const u32 xb = (u32)__shfl((int)hi, wl + 1, 64);
      const u32 yb = (u32)__shfl((int)hi, wl + 2, 64);
      const u32 zb = (u32)__shfl((int)hi, wl + 3, 64);
      if (lane == 0) {
        s_wx = __uint_as_float(xb);
        s_wy = __uint_as_float(yb);
        s_wz = __uint_as_float(zb);
        if (slot == 0)
          ws_idx[b * KSEL + i + 1] = 131071 - (int)((kmax >> 15) & 0x1FFFFu);
      }
    }
    __syncthreads();                                   // b2: winner ready
    sx = s_wx; sy = s_wy; sz = s_wz;
  }
}

__global__ void gather_kernel(const float* __restrict__ points,
                              const int* __restrict__ ws_idx,
                              float* __restrict__ out) {
  const int e = blockIdx.x * 256 + threadIdx.x;   // 0 .. NB*KSEL*NCH-1
  const int c = e & 15;
  const int k = (e >> 4) & (KSEL - 1);
  const int b = e >> 14;
  const int idx = ws_idx[b * KSEL + k];
  out[e] = points[((size_t)b * NPTS + idx) * NCH + c];
}

extern "C" void kernel_launch(void* const* d_in, const int* in_sizes, int n_in,
                              void* d_out, int out_size, void* d_ws, size_t ws_size,
                              hipStream_t stream) {
  const float* points    = (const float*)d_in[0];
  const int*   start_idx = (const int*)d_in[1];
  float*       out       = (float*)d_out;

  u64* cand = (u64*)((char*)d_ws + 4096);
  int* idxl = (int*)((char*)d_ws + 131072);

  // all record words must start tag-invalid (0) every launch (graph-replay safe)
  hipMemsetAsync(cand, 0, 2 * NB * SLOTS * SLOTS * 4 * sizeof(u64), stream);

  fps_kernel<<<NB * SLOTS, TPB, 0, stream>>>(points, start_idx, cand, idxl);
  gather_kernel<<<(NB * KSEL * NCH) / 256, 256, 0, stream>>>(points, idxl, out);
}

// Round 10
// 3527.127 us; speedup vs baseline: 1.0148x; 1.0148x over previous
//
#include <hip/hip_runtime.h>

#define NB    16      // batches
#define NPTS  100000  // points per batch
#define NCH   16      // channels
#define KSEL  1024    // samples
#define SLOTS 8       // blocks per batch
#define TPB   256     // threads per block
#define CHUNK 12500   // NPTS / SLOTS
#define PPT   49      // ceil(CHUNK / TPB)
#define MAGA  0x19u   // 5-bit magic, key words    (never 0, never 0xAA-pattern)
#define MAGB  0x13u   // 5-bit magic, payload words

typedef unsigned long long u64;
typedef unsigned int u32;

// d_ws layout (bytes):
//   [4096, 12288)  : records u64[par=2][NB][word=4][slot=8]
//                    word 0 = keys, 1/2/3 = x/y/z (8 u64 = 64B per word-group;
//                    whole (par,b) region = 256B = 2 lines)
//   [65536, 131072): idx list int[NB][KSEL]
//
// key     = val_bits(32) | invidx(17) | tag(10) | MAGA(5)   (u64 max == winner)
// payload = coord_bits(32) | invidx(17) | tag(10) | MAGB(5)
// invidx = 131071 - idx (max invidx == min idx -> first-index tie-break).
// tag = i+1 (1..1023, never 0 -> memset-0 / 0xAA never match). Tag+magic in
// EVERY u64 -> stale/torn/poison self-rejecting. Single writer per
// (slot,parity,tag); parity double-buffer prevents i/i+2 overwrite (a writer
// reaches tag i+2 only after all readers consumed tag i).
// Contention design (r8-proven, halved): 8 publishers, ONE polling wave per
// block, 32 poll lanes covering the 2-line region.

__device__ __forceinline__ void combine(float ov, int oi, float& v, int& i) {
  if (ov > v || (ov == v && oi < i)) { v = ov; i = oi; }
}

__global__ __launch_bounds__(TPB, 1)
void fps_kernel(const float* __restrict__ points, const int* __restrict__ start_idx,
                u64* __restrict__ ws_cand, int* __restrict__ ws_idx) {
  const int raw  = blockIdx.x;
  const int b    = raw >> 3;           // batch
  const int slot = raw & 7;            // writer/reader id within batch

  const int tid  = threadIdx.x;
  const int lane = tid & 63;
  const int wid  = tid >> 6;           // 4 waves

  const int base = slot * CHUNK;
  const float* __restrict__ pb = points + (size_t)b * NPTS * NCH;

  // ---- load xyz into registers, init min_d ----
  float px[PPT], py[PPT], pz[PPT], md[PPT];
  #pragma unroll
  for (int k = 0; k < PPT; ++k) {
    const int li = tid + (k << 8);
    const bool valid = li < CHUNK;
    float4 p = make_float4(0.f, 0.f, 0.f, 0.f);
    if (valid) p = *reinterpret_cast<const float4*>(pb + (size_t)(base + li) * NCH);
    px[k] = p.x; py[k] = p.y; pz[k] = p.z;
    md[k] = valid ? __builtin_inff() : -__builtin_inff();
  }
  #pragma unroll
  for (int k = 0; k < PPT; ++k)   // keep-live guard against remat/spill games
    asm volatile("" : "+v"(px[k]), "+v"(py[k]), "+v"(pz[k]), "+v"(md[k]));

  __shared__ float s_rv[4];            // per-wave candidates (b1-protected)
  __shared__ int   s_ri[4];
  __shared__ float s_wx, s_wy, s_wz;   // winner broadcast (b2-protected)

  // ---- initial selected point ----
  const int sidx = start_idx[b];
  float sx, sy, sz;
  {
    const float4 p = *reinterpret_cast<const float4*>(pb + (size_t)sidx * NCH);
    sx = p.x; sy = p.y; sz = p.z;
  }
  if (slot == 0 && tid == 0) ws_idx[b * KSEL] = sidx;

  for (int i = 0; i < KSEL - 1; ++i) {
    const int par = i & 1;
    u64* const blk = ws_cand + (((size_t)par * NB + b) << 5);  // 32 u64 per (par,b)

    // ---- distance update + thread-local argmax (bit-exact vs numpy f32:
    //      IEEE intrinsics, left-to-right sum, no FMA contraction) ----
    float bv = -__builtin_inff();
    int   bi = 0x7fffffff;
    #pragma unroll
    for (int k = 0; k < PPT; ++k) {
      const float dx = __fsub_rn(px[k], sx);
      const float dy = __fsub_rn(py[k], sy);
      const float dz = __fsub_rn(pz[k], sz);
      const float d  = __fadd_rn(__fadd_rn(__fmul_rn(dx, dx), __fmul_rn(dy, dy)),
                                 __fmul_rn(dz, dz));
      const float m  = fminf(md[k], d);
      md[k] = m;
      if (m > bv) { bv = m; bi = base + tid + (k << 8); }  // k asc -> first-max kept
    }

    // ---- wave reduce (val, idx), first-index tie-break ----
    #pragma unroll
    for (int m = 32; m >= 1; m >>= 1) {
      const float ov = __shfl_xor(bv, m, 64);
      const int   oi = __shfl_xor(bi, m, 64);
      combine(ov, oi, bv, bi);
    }
    if (lane == 0) { s_rv[wid] = bv; s_ri[wid] = bi; }
    __syncthreads();                                   // b1: candidates ready

    // ---- block combine (every thread) ----
    bv = s_rv[0]; bi = s_ri[0];
    #pragma unroll
    for (int w = 1; w < 4; ++w) combine(s_rv[w], s_ri[w], bv, bi);

    const u32 tm = (u32)(i + 1) << 5;

    // ---- owner thread publishes {key,x,y,z} to the 4 SoA word-groups ----
    const int local = bi - base;
    if (tid == (local & 255)) {
      const int kk = local >> 8;
      float ox = 0.f, oy = 0.f, oz = 0.f;
      #pragma unroll
      for (int k = 0; k < PPT; ++k)   // static-index select (arrays stay in VGPRs)
        if (k == kk) { ox = px[k]; oy = py[k]; oz = pz[k]; }
      const u32 inv = 131071u - (u32)bi;
      const u32 loA = (inv << 15) | tm | MAGA;
      const u32 loB = (inv << 15) | tm | MAGB;
      __hip_atomic_store(blk      + slot, ((u64)__float_as_uint(bv) << 32) | loA,
                         __ATOMIC_RELAXED, __HIP_MEMORY_SCOPE_AGENT);
      __hip_atomic_store(blk +  8 + slot, ((u64)__float_as_uint(ox) << 32) | loB,
                         __ATOMIC_RELAXED, __HIP_MEMORY_SCOPE_AGENT);
      __hip_atomic_store(blk + 16 + slot, ((u64)__float_as_uint(oy) << 32) | loB,
                         __ATOMIC_RELAXED, __HIP_MEMORY_SCOPE_AGENT);
      __hip_atomic_store(blk + 24 + slot, ((u64)__float_as_uint(oz) << 32) | loB,
                         __ATOMIC_RELAXED, __HIP_MEMORY_SCOPE_AGENT);
    }

    // ---- wave 0 ONLY polls the 2-line region (32 lanes, 1 u64 each) ----
    if (wid == 0) {
      const bool active = lane < 32;
      const int  word   = lane >> 3;               // 0=key,1=x,2=y,3=z
      const u32  want   = tm | (word == 0 ? MAGA : MAGB);
      u64 q = 0;
      for (;;) {
        if (active) q = __hip_atomic_load(blk + lane, __ATOMIC_RELAXED, __HIP_MEMORY_SCOPE_AGENT);
        if (__all(!active || (((u32)q & 0x7FFFu) == want))) break;
        __builtin_amdgcn_s_sleep(1);
      }
      // max over the 8 key lanes (0..7): xor-net {1,2,4} closed on them
      u64 key = (active && word == 0) ? q : 0;
      #pragma unroll
      for (int m = 4; m >= 1; m >>= 1) {
        const u64 o = __shfl_xor(key, m, 64);
        if (o > key) key = o;
      }
      const u64 kmax = __shfl(key, 0, 64);          // broadcast winner key
      const unsigned long long ball = __ballot(active && word == 0 && q == kmax);
      const int ws = __ffsll(ball) - 1;             // winning slot (keys unique)
      const u32 hi = (u32)(q >> 32);
      const u32 xb = (u32)__shfl((int)hi,  8 + ws, 64);
      const u32 yb = (u32)__shfl((int)hi, 16 + ws, 64);
      const u32 zb = (u32)__shfl((int)hi, 24 + ws, 64);
      if (lane == 0) {
        s_wx = __uint_as_float(xb);
        s_wy = __uint_as_float(yb);
        s_wz = __uint_as_float(zb);
        if (slot == 0)
          ws_idx[b * KSEL + i + 1] = 131071 - (int)((kmax >> 15) & 0x1FFFFu);
      }
    }
    __syncthreads();                                   // b2: winner ready
    sx = s_wx; sy = s_wy; sz = s_wz;
  }
}

__global__ void gather_kernel(const float* __restrict__ points,
                              const int* __restrict__ ws_idx,
                              float* __restrict__ out) {
  const int e = blockIdx.x * 256 + threadIdx.x;   // 0 .. NB*KSEL*NCH-1
  const int c = e & 15;
  const int k = (e >> 4) & (KSEL - 1);
  const int b = e >> 14;
  const int idx = ws_idx[b * KSEL + k];
  out[e] = points[((size_t)b * NPTS + idx) * NCH + c];
}

extern "C" void kernel_launch(void* const* d_in, const int* in_sizes, int n_in,
                              void* d_out, int out_size, void* d_ws, size_t ws_size,
                              hipStream_t stream) {
  const float* points    = (const float*)d_in[0];
  const int*   start_idx = (const int*)d_in[1];
  float*       out       = (float*)d_out;

  u64* cand = (u64*)((char*)d_ws + 4096);
  int* idxl = (int*)((char*)d_ws + 65536);

  // all record words must start tag-invalid (0) every launch (graph-replay safe)
  hipMemsetAsync(cand, 0, 2 * NB * 4 * SLOTS * sizeof(u64), stream);

  fps_kernel<<<NB * SLOTS, TPB, 0, stream>>>(points, start_idx, cand, idxl);
  gather_kernel<<<(NB * KSEL * NCH) / 256, 256, 0, stream>>>(points, idxl, out);
}